// Round 6
// baseline (124.426 us; speedup 1.0000x reference)
//
#include <hip/hip_runtime.h>

// StochaPolicy: out[b,0:32] = phi_m @ w_m.T + b_m ; out[b,32:64] = exp(clip(phi_s @ w_s.T + b_s))
// phi_h[b,k] = exp(-(|x|^2 - 2 x.C_h[k] + |C_h[k]|^2) / (2|sigma_h[k]|))
// B=32768 D=256 K=1024 A=32.
//
// R18: prep consolidation. R17's policy_main is below the 44us harness fills
// (invisible in top-5); totals drifted 116.9->123.5 across R12->R17 while
// policy halved -- the growing term is prep: 8720 workgroups (1 per 4 obs
// rows, ~500 cycles work each) serialized between the ws-poison fill and
// policy_main; its dispatch ramp + drain is pure timeline addition. R18 packs
// the obs-quant into 1024 blocks x 8 grid-strided row-iterations (byte-
// identical per-row math/layout; 8 independent loads per thread = better ILP
// per wg), obs branch dispatched first, centers/wt after: 1552 wg total.
// policy_main byte-identical to verified R17 (cross-step software pipeline,
// (256,4)).

typedef float floatx4 __attribute__((ext_vector_type(4)));
typedef int   intx4  __attribute__((ext_vector_type(4)));
typedef unsigned int u32;
typedef unsigned char u8;

constexpr float LOG2E = 1.4426950408889634f;
constexpr float QS    = 25.4f;                 // 127/5 quant multiplier
constexpr float SINV2 = (5.0f / 127.0f) * (5.0f / 127.0f);

__device__ __forceinline__ u32 pk_fp8(float a, float b, float c, float d) {
  u32 v = __builtin_amdgcn_cvt_pk_fp8_f32(a, b, 0u, 0);   // bytes 0,1
  v = __builtin_amdgcn_cvt_pk_fp8_f32(c, d, v, 1);        // bytes 2,3
  return v;
}
__device__ __forceinline__ long mk64(u32 lo, u32 hi) {
  return (long)lo | ((long)hi << 32);
}
__device__ __forceinline__ int q8(float x) {
  return (int)rintf(fminf(fmaxf(x * QS, -127.f), 127.f));
}
__device__ __forceinline__ u32 pk_i8(int a, int b, int c, int d) {
  return (u32)(a & 255) | ((u32)(b & 255) << 8) | ((u32)(c & 255) << 16) | ((u32)(d & 255) << 24);
}

// ---------- merged prologue ----------
// blk < 1024  : obs quant -> qb (fragment layout) + hx2f, 8 rows-groups/block
// blk < 1536  : center quant -> Cb2 + a2g/g2n
// blk < 1552  : wt builder
__global__ void prep(const float* __restrict__ mC, const float* __restrict__ mS,
                     const float* __restrict__ sC, const float* __restrict__ sS,
                     const float* __restrict__ mw, const float* __restrict__ sw,
                     const float* __restrict__ obs,
                     u8* __restrict__ Cb2, float* __restrict__ a2g,
                     float* __restrict__ g2n, u8* __restrict__ wt,
                     u8* __restrict__ qb, float* __restrict__ hx2f)
{
  const int blk = blockIdx.x;
  if (blk < 1024) {
    // obs quant: wave = one row per iteration, 8 iterations.
    // Layout: qb[T][ks][q*16+c][16B], T=row>>4, c=row&15; element d=t*4+{0..3}
    // -> ks=t>>4, q=(t>>2)&3, byte-in-slot j0=(t&3)*4. Matches policy's
    // lane-coalesced ob read. Per-row math byte-identical to R15/R17.
    const int wq = threadIdx.x >> 6;
    const int t  = threadIdx.x & 63;
    const int ks = t >> 4, q = (t >> 2) & 3, j0 = (t & 3) * 4;
    #pragma unroll
    for (int it = 0; it < 8; ++it) {
      const int row = blk * 32 + it * 4 + wq;   // 0..32767
      float4 f = *(const float4*)(obs + (size_t)row * 256 + t * 4);
      int i0 = q8(f.x), i1 = q8(f.y), i2 = q8(f.z), i3 = q8(f.w);
      const int T = row >> 4, c = row & 15;
      *(u32*)(qb + (size_t)T * 4096 + ks * 1024 + q * 256 + c * 16 + j0) =
          pk_i8(i0, i1, i2, i3);
      int is = i0 * i0 + i1 * i1 + i2 * i2 + i3 * i3;
      for (int off = 32; off > 0; off >>= 1) is += __shfl_down(is, off, 64);
      if (t == 0) hx2f[row] = 0.5f * (float)is;  // exact: is <= 4.13e6 < 2^24
    }
  } else if (blk < 1536) {
    const int wq = threadIdx.x >> 6;
    const int t  = threadIdx.x & 63;
    const int b  = (blk - 1024) * 4 + wq;   // 0..2047 combined center index
    const int half = b >> 10;
    const int k = b & 1023;
    const float* src = (half ? sC : mC) + (size_t)k * 256;
    float4 f = *(const float4*)(src + t * 4);
    int i0 = q8(f.x), i1 = q8(f.y), i2 = q8(f.z), i3 = q8(f.w);
    const int ct = b >> 6, row = b & 63;
    const int wvv = row >> 4, cc = row & 15;
    const int ks = t >> 4, qq = (t >> 2) & 3, j0 = (t & 3) * 4;
    *(u32*)(Cb2 + (size_t)ct * 16384 + wvv * 4096 + (ks * 64 + qq * 16 + cc) * 16 + j0) =
        pk_i8(i0, i1, i2, i3);
    int is = i0 * i0 + i1 * i1 + i2 * i2 + i3 * i3;
    for (int off = 32; off > 0; off >>= 1) is += __shfl_down(is, off, 64);
    if (t == 0) {
      float sig = fabsf((half ? sS : mS)[k]);
      float t2 = SINV2 * LOG2E * 0.5f / sig;
      a2g[b] = 2.f * t2;
      g2n[b] = -t2 * (float)is;
    }
  } else {
    // wt builder: block = pair m, thread = tid of the main kernel
    const int m   = blk - 1536;             // 0..15
    const int tid = threadIdx.x;
    const int wv  = tid >> 6;
    const int lane = tid & 63;
    const int c   = lane & 15;
    const int q   = lane >> 4;
    const int kbE = ((2 * m) & 15) * 64 + 16 * wv + 4 * q;
    const float* src = (m < 8) ? mw : sw;   // w_h[a][k], A=32 x K=1024
    float4 f00 = *(const float4*)(src + (size_t)c * 1024 + kbE);
    float4 f01 = *(const float4*)(src + (size_t)c * 1024 + kbE + 64);
    float4 f10 = *(const float4*)(src + (size_t)(16 + c) * 1024 + kbE);
    float4 f11 = *(const float4*)(src + (size_t)(16 + c) * 1024 + kbE + 64);
    uint4 o;
    o.x = pk_fp8(f00.x, f00.y, f00.z, f00.w);   // w0lo: even-tile K bytes
    o.y = pk_fp8(f01.x, f01.y, f01.z, f01.w);   // w0hi: odd-tile K bytes
    o.z = pk_fp8(f10.x, f10.y, f10.z, f10.w);   // w1lo
    o.w = pk_fp8(f11.x, f11.y, f11.z, f11.w);   // w1hi
    *(uint4*)(wt + ((size_t)m * 256 + tid) * 16) = o;
  }
}

// ---------- main fused kernel (byte-identical to verified R17) ----------
// block = (row-block rb, half). 32 rows, the half's 1024 centers = 8 pairs.
__global__ __launch_bounds__(256, 4)
void policy_main(const u8* __restrict__ qb,
                 const float* __restrict__ hx2f,
                 const u8* __restrict__ Cb2,
                 const float* __restrict__ a2g,
                 const float* __restrict__ g2n,
                 const u8* __restrict__ wt,
                 const float* __restrict__ mbias,
                 const float* __restrict__ sbias,
                 float* __restrict__ out)
{
  // LDS: epilogue reduction only. red[wv][b=32][a=36pad] f32 = 18432 B.
  __shared__ __align__(16) float red[4608];

  const int tid  = threadIdx.x;
  const int lane = tid & 63;
  const int wv   = tid >> 6;        // wave 0..3 : kc slice [16wv,16wv+16)
  const int c    = lane & 15;
  const int q    = lane >> 4;       // quad 0..3
  const int half = blockIdx.x & 1;  // 0 = mean net, 1 = std net
  const int row0 = (blockIdx.x >> 1) * 32;
  const int kslc = 16 * wv + 4 * q; // lane's kc sub-slice base within tile
  const int cfo  = wv * 4096 + lane * 16;  // coalesced fragment base

  // per-half base pointers
  const u8*    cbh = Cb2 + (size_t)half * (16 * 16384);
  const float* a2h = a2g + half * 1024;
  const float* g2h = g2n + half * 1024;
  const u8*    wtl = wt + (size_t)half * 32768 + (size_t)tid * 16;

  // chunk j of this lane's tile-fragment lives at cfo + j*1024 (coalesced)
#define LOADCF(CF, t)                                                     \
  { const u8* g0_ = cbh + (size_t)(t) * 16384 + cfo;                      \
    CF[0] = *(const intx4*)(g0_);                                         \
    CF[1] = *(const intx4*)(g0_ + 1024);                                  \
    CF[2] = *(const intx4*)(g0_ + 2048);                                  \
    CF[3] = *(const intx4*)(g0_ + 3072); }

  intx4 cfU[4], cfV[4];
  LOADCF(cfU, 0)
  LOADCF(cfV, 1)

  // ---- obs B-fragments straight from qb (lane-coalesced 16B loads) ----
  intx4 ob[2][4];                   // 32 regs (MFMA operands)
  {
    const u8* qrow = qb + (size_t)(row0 >> 4) * 4096 + lane * 16;
    #pragma unroll
    for (int nt = 0; nt < 2; ++nt)
      #pragma unroll
      for (int ks = 0; ks < 4; ++ks)
        ob[nt][ks] = *(const intx4*)(qrow + nt * 4096 + ks * 1024);
  }

  float hx2[2];
  hx2[0] = hx2f[row0 + c];
  hx2[1] = hx2f[row0 + 16 + c];

  const intx4 Z4i = {0, 0, 0, 0};
  const floatx4 Z4 = {0.f, 0.f, 0.f, 0.f};
  floatx4 acc[2][2];                // [a2i][nt], static indexing only
  #pragma unroll
  for (int a2i = 0; a2i < 2; ++a2i)
    #pragma unroll
    for (int nt = 0; nt < 2; ++nt) acc[a2i][nt] = Z4;

  intx4 a1E[2], a1O[2];             // current pair's GEMM1 accumulators
  u32 pE[2], pc[2];

#define GEMM1PAIR()                                                             \
  { _Pragma("unroll")                                                           \
    for (int nt = 0; nt < 2; ++nt) {                                            \
      a1E[nt] = __builtin_amdgcn_mfma_i32_16x16x64_i8(cfU[0], ob[nt][0], Z4i, 0, 0, 0); \
      a1O[nt] = __builtin_amdgcn_mfma_i32_16x16x64_i8(cfV[0], ob[nt][0], Z4i, 0, 0, 0); \
    }                                                                           \
    _Pragma("unroll")                                                           \
    for (int ks = 1; ks < 4; ++ks) {                                            \
      _Pragma("unroll")                                                         \
      for (int nt = 0; nt < 2; ++nt) {                                          \
        a1E[nt] = __builtin_amdgcn_mfma_i32_16x16x64_i8(cfU[ks], ob[nt][ks], a1E[nt], 0, 0, 0); \
        a1O[nt] = __builtin_amdgcn_mfma_i32_16x16x64_i8(cfV[ks], ob[nt][ks], a1O[nt], 0, 0, 0); \
      }                                                                         \
    } }

#define EXPP(A1, AC, GC, DST)                                                   \
  { _Pragma("unroll")                                                           \
    for (int nt = 0; nt < 2; ++nt) {                                            \
      float t0 = (float)A1[nt][0] - hx2[nt], t1 = (float)A1[nt][1] - hx2[nt];   \
      float t2 = (float)A1[nt][2] - hx2[nt], t3 = (float)A1[nt][3] - hx2[nt];   \
      DST[nt] = pk_fp8(__builtin_amdgcn_exp2f(fmaf(AC.x, t0, GC.x)),            \
                       __builtin_amdgcn_exp2f(fmaf(AC.y, t1, GC.y)),            \
                       __builtin_amdgcn_exp2f(fmaf(AC.z, t2, GC.z)),            \
                       __builtin_amdgcn_exp2f(fmaf(AC.w, t3, GC.w))); } }

#define GEMM2P(WV4)                                                             \
  { long wA0 = mk64(WV4.x, WV4.y), wA1 = mk64(WV4.z, WV4.w);                    \
    _Pragma("unroll")                                                           \
    for (int nt = 0; nt < 2; ++nt) {                                            \
      long pb = mk64(pE[nt], pc[nt]);                                           \
      acc[0][nt] = __builtin_amdgcn_mfma_f32_16x16x32_fp8_fp8(wA0, pb, acc[0][nt], 0, 0, 0); \
      acc[1][nt] = __builtin_amdgcn_mfma_f32_16x16x32_fp8_fp8(wA1, pb, acc[1][nt], 0, 0, 0); \
    } }

  // ---- software-pipelined K loop ----
  // coef(0) + GEMM1(pair 0) in prologue; iter mm overlaps GEMM1(mm+1) with
  // EXPP(mm)/GEMM2(mm); cf prefetch runs one pair further ahead.
  uint4  wv4c = *(const uint4*)(wtl);
  float4 acEc = *(const float4*)(a2h + kslc);
  float4 gcEc = *(const float4*)(g2h + kslc);
  float4 acOc = *(const float4*)(a2h + 64 + kslc);
  float4 gcOc = *(const float4*)(g2h + 64 + kslc);

  GEMM1PAIR()                       // pair 0 (tiles 0,1)
  LOADCF(cfU, 2) LOADCF(cfV, 3)     // pair 1

  #pragma unroll
  for (int mm = 0; mm < 8; ++mm) {
    // snapshot current pair's GEMM1 results (register copy; SSA-renamed away)
    intx4 s1E[2], s1O[2];
    s1E[0] = a1E[0]; s1E[1] = a1E[1];
    s1O[0] = a1O[0]; s1O[1] = a1O[1];

    // issue next pair's coef loads early (full STEP to cover L2 latency)
    uint4  wv4n = wv4c;
    float4 acEn = acEc, gcEn = gcEc, acOn = acOc, gcOn = gcOc;
    if (mm < 7) {
      wv4n = *(const uint4*)(wtl + (size_t)(mm + 1) * 4096);
      acEn = *(const float4*)(a2h + (2 * (mm + 1)) * 64 + kslc);
      gcEn = *(const float4*)(g2h + (2 * (mm + 1)) * 64 + kslc);
      acOn = *(const float4*)(a2h + (2 * (mm + 1) + 1) * 64 + kslc);
      gcOn = *(const float4*)(g2h + (2 * (mm + 1) + 1) * 64 + kslc);
    }

    // next pair's GEMM1 -- independent of EXPP/GEMM2 below (matrix pipe
    // overlaps VALU exp/pack of the current pair)
    if (mm < 7) {
      GEMM1PAIR()                   // pair mm+1 (tiles 2mm+2, 2mm+3)
    }
    if (mm < 6) {
      LOADCF(cfU, 2 * (mm + 2)) LOADCF(cfV, 2 * (mm + 2) + 1)  // pair mm+2
    }

    EXPP(s1E, acEc, gcEc, pE)
    EXPP(s1O, acOc, gcOc, pc)
    GEMM2P(wv4c)

    wv4c = wv4n; acEc = acEn; gcEc = gcEn; acOc = acOn; gcOc = gcOn;
  }
#undef GEMM1PAIR
#undef EXPP
#undef GEMM2P
#undef LOADCF

  // ---- epilogue: cross-wave reduction ----
  // red[wv][b=32][a=36pad]; lane(c,q) reg r holds a = a2i*16+4q+r, b = nt*16+c
  {
    float* myr = red + wv * 1152;
    #pragma unroll
    for (int a2i = 0; a2i < 2; ++a2i)
      #pragma unroll
      for (int nt = 0; nt < 2; ++nt)
        *(floatx4*)(myr + (nt * 16 + c) * 36 + a2i * 16 + 4 * q) = acc[a2i][nt];
  }
  __syncthreads();

  const float* bias = half ? sbias : mbias;
  #pragma unroll
  for (int i = 0; i < 4; ++i) {
    int idx = tid + 256 * i;        // 0..1023
    int a = idx & 31;
    int b = idx >> 5;               // 0..31
    float v = red[b * 36 + a] + red[1152 + b * 36 + a] +
              red[2304 + b * 36 + a] + red[3456 + b * 36 + a];
    v += bias[a];
    if (half) {                     // block-uniform branch
      v = fminf(fmaxf(v, -20.f), 2.f);
      v = __builtin_amdgcn_exp2f(v * LOG2E);
    }
    out[(size_t)(row0 + b) * 64 + half * 32 + a] = v;
  }
}

extern "C" void kernel_launch(void* const* d_in, const int* in_sizes, int n_in,
                              void* d_out, int out_size, void* d_ws, size_t ws_size,
                              hipStream_t stream) {
  const float* obs = (const float*)d_in[0];
  const float* mC  = (const float*)d_in[1];
  const float* mS  = (const float*)d_in[2];
  const float* mW  = (const float*)d_in[3];
  const float* mB  = (const float*)d_in[4];
  const float* sC  = (const float*)d_in[5];
  const float* sS  = (const float*)d_in[6];
  const float* sW  = (const float*)d_in[7];
  const float* sB  = (const float*)d_in[8];
  float* out = (float*)d_out;

  // workspace: Cb2[512KB] | a2g[8KB] | g2n[8KB] | wt[64KB] | qb[8MB] @640KB | hx2f[128KB]
  u8*    Cb2  = (u8*)d_ws;
  float* a2g  = (float*)((char*)d_ws + 524288);
  float* g2n  = a2g + 2048;
  u8*    wt   = (u8*)(g2n + 2048);
  u8*    qb   = (u8*)d_ws + 655360;
  float* hx2f = (float*)((char*)d_ws + 655360 + 8388608);

  prep<<<1552, 256, 0, stream>>>(mC, mS, sC, sS, mW, sW, obs, Cb2, a2g, g2n, wt, qb, hx2f);
  policy_main<<<2048, 256, 0, stream>>>(qb, hx2f, Cb2, a2g, g2n, wt, mB, sB, out);
}

// Round 7
// 117.264 us; speedup vs baseline: 1.0611x; 1.0611x over previous
//
#include <hip/hip_runtime.h>

// StochaPolicy: out[b,0:32] = phi_m @ w_m.T + b_m ; out[b,32:64] = exp(clip(phi_s @ w_s.T + b_s))
// phi_h[b,k] = exp(-(|x|^2 - 2 x.C_h[k] + |C_h[k]|^2) / (2|sigma_h[k]|))
// B=32768 D=256 K=1024 A=32.
//
// R19: return to the twice-verified R12 config (grid 512, 64-row blocks, obs
// quant in-kernel, prep 528wg, ws 592KB) -- the only config whose total obeys
// fill+prep+policy additively (116.6/116.9 both measurements); every
// grid-2048 variant carries a ~+30us config-correlated overhead that made
// totals insensitive to policy gains (R12->R14: policy -28us, total +2.7).
// On top of R12, apply the R17-verified cross-step software pipeline:
//   iter mm: snapshot a1 ; load coef(mm+1) ; GEMM1PAIR(mm+1) [independent] ;
//            prefetch cf(mm+2) ; EXPP(mm from snapshot) ; GEMM2(mm)
// so the matrix pipe computes pair mm+1 while the VALU does exp2/pack of pair
// mm, and coef loads get a full STEP to cover L2 latency. launch_bounds
// (256,2): 256-VGPR cap, ~80 regs headroom for snapshot+next-coef. Math
// bit-identical to R12.

typedef float floatx4 __attribute__((ext_vector_type(4)));
typedef int   intx4  __attribute__((ext_vector_type(4)));
typedef unsigned int u32;
typedef unsigned char u8;

constexpr float LOG2E = 1.4426950408889634f;
constexpr float QS    = 25.4f;                 // 127/5 quant multiplier
constexpr float SINV2 = (5.0f / 127.0f) * (5.0f / 127.0f);

__device__ __forceinline__ u32 pk_fp8(float a, float b, float c, float d) {
  u32 v = __builtin_amdgcn_cvt_pk_fp8_f32(a, b, 0u, 0);   // bytes 0,1
  v = __builtin_amdgcn_cvt_pk_fp8_f32(c, d, v, 1);        // bytes 2,3
  return v;
}
__device__ __forceinline__ long mk64(u32 lo, u32 hi) {
  return (long)lo | ((long)hi << 32);
}
__device__ __forceinline__ int q8(float x) {
  return (int)rintf(fminf(fmaxf(x * QS, -127.f), 127.f));
}
__device__ __forceinline__ u32 pk_i8(int a, int b, int c, int d) {
  return (u32)(a & 255) | ((u32)(b & 255) << 8) | ((u32)(c & 255) << 16) | ((u32)(d & 255) << 24);
}

// ---------- merged prologue (identical to R12) ----------
__global__ void prep(const float* __restrict__ mC, const float* __restrict__ mS,
                     const float* __restrict__ sC, const float* __restrict__ sS,
                     const float* __restrict__ mw, const float* __restrict__ sw,
                     u8* __restrict__ Cb2, float* __restrict__ a2g,
                     float* __restrict__ g2n, u8* __restrict__ wt)
{
  const int blk = blockIdx.x;
  if (blk < 512) {
    const int wq = threadIdx.x >> 6;
    const int t  = threadIdx.x & 63;
    const int b  = blk * 4 + wq;            // 0..2047 combined center index
    const int half = b >> 10;
    const int k = b & 1023;
    const float* src = (half ? sC : mC) + (size_t)k * 256;
    float4 f = *(const float4*)(src + t * 4);
    int i0 = q8(f.x), i1 = q8(f.y), i2 = q8(f.z), i3 = q8(f.w);
    const int ct = b >> 6, row = b & 63;
    const int wvv = row >> 4, cc = row & 15;
    const int ks = t >> 4, qq = (t >> 2) & 3, j0 = (t & 3) * 4;
    *(u32*)(Cb2 + (size_t)ct * 16384 + wvv * 4096 + (ks * 64 + qq * 16 + cc) * 16 + j0) =
        pk_i8(i0, i1, i2, i3);
    int is = i0 * i0 + i1 * i1 + i2 * i2 + i3 * i3;
    for (int off = 32; off > 0; off >>= 1) is += __shfl_down(is, off, 64);
    if (t == 0) {
      float sig = fabsf((half ? sS : mS)[k]);
      float t2 = SINV2 * LOG2E * 0.5f / sig;
      a2g[b] = 2.f * t2;
      g2n[b] = -t2 * (float)is;
    }
  } else {
    // wt builder: block = pair m, thread = tid of the main kernel
    const int m   = blk - 512;              // 0..15
    const int tid = threadIdx.x;
    const int wv  = tid >> 6;
    const int lane = tid & 63;
    const int c   = lane & 15;
    const int q   = lane >> 4;
    const int kbE = ((2 * m) & 15) * 64 + 16 * wv + 4 * q;
    const float* src = (m < 8) ? mw : sw;   // w_h[a][k], A=32 x K=1024
    float4 f00 = *(const float4*)(src + (size_t)c * 1024 + kbE);
    float4 f01 = *(const float4*)(src + (size_t)c * 1024 + kbE + 64);
    float4 f10 = *(const float4*)(src + (size_t)(16 + c) * 1024 + kbE);
    float4 f11 = *(const float4*)(src + (size_t)(16 + c) * 1024 + kbE + 64);
    uint4 o;
    o.x = pk_fp8(f00.x, f00.y, f00.z, f00.w);   // w0lo: even-tile K bytes
    o.y = pk_fp8(f01.x, f01.y, f01.z, f01.w);   // w0hi: odd-tile K bytes
    o.z = pk_fp8(f10.x, f10.y, f10.z, f10.w);   // w1lo
    o.w = pk_fp8(f11.x, f11.y, f11.z, f11.w);   // w1hi
    *(uint4*)(wt + ((size_t)m * 256 + tid) * 16) = o;
  }
}

// ---------- main fused kernel (R12 structure + cross-step pipeline) ----------
__global__ __launch_bounds__(256, 2)
void policy_main(const float* __restrict__ obs,
                 const u8* __restrict__ Cb2,
                 const float* __restrict__ a2g,
                 const float* __restrict__ g2n,
                 const u8* __restrict__ wt,
                 const float* __restrict__ mbias,
                 const float* __restrict__ sbias,
                 float* __restrict__ out)
{
  // LDS: prologue obs i8 tile [0,16384) + x2p [16384,20736).
  // Epilogue red[4][64][68] f32 (69632 B) aliases from 0.
  __shared__ __align__(16) char smem[69888];
  float* x2p = (float*)(smem + 16384);
  float* red = (float*)smem;

  const int tid  = threadIdx.x;
  const int lane = tid & 63;
  const int wv   = tid >> 6;        // wave 0..3 : kc slice [16wv,16wv+16)
  const int c    = lane & 15;
  const int q    = lane >> 4;       // quad 0..3
  const int row0 = blockIdx.x * 64;
  const int kslc = 16 * wv + 4 * q; // lane's kc sub-slice base within tile
  const int cfo  = wv * 4096 + lane * 16;  // coalesced fragment base
  const u8* wtl  = wt + (size_t)tid * 16;  // lane's wt column

  // chunk j of this lane's tile-fragment lives at cfo + j*1024 (coalesced)
#define LOADCF(CF, t)                                                     \
  { const u8* g0_ = Cb2 + (size_t)(t) * 16384 + cfo;                      \
    CF[0] = *(const intx4*)(g0_);                                         \
    CF[1] = *(const intx4*)(g0_ + 1024);                                  \
    CF[2] = *(const intx4*)(g0_ + 2048);                                  \
    CF[3] = *(const intx4*)(g0_ + 3072); }

  intx4 cfU[4], cfV[4];
  LOADCF(cfU, 0)
  LOADCF(cfV, 1)

  // ---- convert obs tile fp32 -> i8 into LDS (XOR-swizzled 16B slots) + x2 ----
  #pragma unroll
  for (int i = 0; i < 4; ++i) {
    int s = i * 256 + tid;          // 16B slot 0..1023
    int row = s >> 4;
    int s16 = s & 15;
    int l16 = s16 ^ (row & 15);
    const float* src = obs + (size_t)(row0 + row) * 256 + l16 * 16;
    float4 f0 = ((const float4*)src)[0];
    float4 f1 = ((const float4*)src)[1];
    float4 f2 = ((const float4*)src)[2];
    float4 f3 = ((const float4*)src)[3];
    int a0 = q8(f0.x), a1v = q8(f0.y), a2v = q8(f0.z), a3 = q8(f0.w);
    int b0 = q8(f1.x), b1 = q8(f1.y), b2 = q8(f1.z), b3 = q8(f1.w);
    int c0 = q8(f2.x), c1 = q8(f2.y), c2 = q8(f2.z), c3 = q8(f2.w);
    int d0 = q8(f3.x), d1 = q8(f3.y), d2 = q8(f3.z), d3 = q8(f3.w);
    uint4 pk;
    pk.x = pk_i8(a0, a1v, a2v, a3);
    pk.y = pk_i8(b0, b1, b2, b3);
    pk.z = pk_i8(c0, c1, c2, c3);
    pk.w = pk_i8(d0, d1, d2, d3);
    *(uint4*)(smem + s * 16) = pk;
    int is = a0*a0 + a1v*a1v + a2v*a2v + a3*a3
           + b0*b0 + b1*b1 + b2*b2 + b3*b3
           + c0*c0 + c1*c1 + c2*c2 + c3*c3
           + d0*d0 + d1*d1 + d2*d2 + d3*d3;
    x2p[row * 16 + s16] = (float)is;
  }
  __syncthreads();   // obs tile + partials visible

  // ---- preload obs B-fragments: ob[nt][ks] = obs[b=nt*16+c][d=64ks+16q..+16] ----
  intx4 ob[4][4];                   // 64 regs (MFMA operands)
  #pragma unroll
  for (int nt = 0; nt < 4; ++nt) {
    const int row = nt * 16 + c;
    #pragma unroll
    for (int ks = 0; ks < 4; ++ks) {
      int slot = (4 * ks + q) ^ (row & 15);
      ob[nt][ks] = *(const intx4*)(smem + row * 256 + slot * 16);
    }
  }
  if (tid < 64) {
    float s = 0.f;
    #pragma unroll
    for (int j = 0; j < 16; j += 4) {
      float4 a = *(const float4*)(x2p + tid * 16 + j);
      s += a.x + a.y + a.z + a.w;
    }
    x2p[1024 + tid] = s;
  }
  __syncthreads();   // x2 sums visible (last barrier before epilogue)

  float hx2[4];
  #pragma unroll
  for (int nt = 0; nt < 4; ++nt) hx2[nt] = 0.5f * x2p[1024 + nt * 16 + c];

  const intx4 Z4i = {0, 0, 0, 0};
  const floatx4 Z4 = {0.f, 0.f, 0.f, 0.f};
  floatx4 acc2m[2][4], acc2s[2][4];   // 64 regs, static indexing only
  #pragma unroll
  for (int a2i = 0; a2i < 2; ++a2i)
    #pragma unroll
    for (int nt = 0; nt < 4; ++nt) {
      acc2m[a2i][nt] = Z4;
      acc2s[a2i][nt] = Z4;
    }

  intx4 a1E[4], a1O[4];             // 8 independent accumulator chains
  u32 pE[4], pc[4];

  // interleaved GEMM1 for BOTH tiles of a pair: 8 chains, dep distance = 8 issues
#define GEMM1PAIR()                                                             \
  { _Pragma("unroll")                                                           \
    for (int nt = 0; nt < 4; ++nt) {                                            \
      a1E[nt] = __builtin_amdgcn_mfma_i32_16x16x64_i8(cfU[0], ob[nt][0], Z4i, 0, 0, 0); \
      a1O[nt] = __builtin_amdgcn_mfma_i32_16x16x64_i8(cfV[0], ob[nt][0], Z4i, 0, 0, 0); \
    }                                                                           \
    _Pragma("unroll")                                                           \
    for (int ks = 1; ks < 4; ++ks) {                                            \
      _Pragma("unroll")                                                         \
      for (int nt = 0; nt < 4; ++nt) {                                          \
        a1E[nt] = __builtin_amdgcn_mfma_i32_16x16x64_i8(cfU[ks], ob[nt][ks], a1E[nt], 0, 0, 0); \
        a1O[nt] = __builtin_amdgcn_mfma_i32_16x16x64_i8(cfV[ks], ob[nt][ks], a1O[nt], 0, 0, 0); \
      }                                                                         \
    } }

#define EXPP(A1, AC, GC, DST)                                                   \
  { _Pragma("unroll")                                                           \
    for (int nt = 0; nt < 4; ++nt) {                                            \
      float t0 = (float)A1[nt][0] - hx2[nt], t1 = (float)A1[nt][1] - hx2[nt];   \
      float t2 = (float)A1[nt][2] - hx2[nt], t3 = (float)A1[nt][3] - hx2[nt];   \
      DST[nt] = pk_fp8(__builtin_amdgcn_exp2f(fmaf(AC.x, t0, GC.x)),            \
                       __builtin_amdgcn_exp2f(fmaf(AC.y, t1, GC.y)),            \
                       __builtin_amdgcn_exp2f(fmaf(AC.z, t2, GC.z)),            \
                       __builtin_amdgcn_exp2f(fmaf(AC.w, t3, GC.w))); } }

#define GEMM2P(ACC, WV4)                                                        \
  { long wA0 = mk64(WV4.x, WV4.y), wA1 = mk64(WV4.z, WV4.w);                    \
    _Pragma("unroll")                                                           \
    for (int nt = 0; nt < 4; ++nt) {                                            \
      long pb = mk64(pE[nt], pc[nt]);                                           \
      ACC[0][nt] = __builtin_amdgcn_mfma_f32_16x16x32_fp8_fp8(wA0, pb, ACC[0][nt], 0, 0, 0); \
      ACC[1][nt] = __builtin_amdgcn_mfma_f32_16x16x32_fp8_fp8(wA1, pb, ACC[1][nt], 0, 0, 0); \
    } }

  // ---- software-pipelined K loop (R17 transform at R12 geometry) ----
  // coef(0) + GEMM1(pair 0) in prologue; iter mm overlaps GEMM1(mm+1) with
  // EXPP(mm)/GEMM2(mm); cf prefetch runs one pair further ahead.
  uint4  wv4c = *(const uint4*)(wtl);
  float4 acEc = *(const float4*)(a2g + kslc);
  float4 gcEc = *(const float4*)(g2n + kslc);
  float4 acOc = *(const float4*)(a2g + 64 + kslc);
  float4 gcOc = *(const float4*)(g2n + 64 + kslc);

  GEMM1PAIR()                       // pair 0 (tiles 0,1)
  LOADCF(cfU, 2) LOADCF(cfV, 3)     // pair 1

  #pragma unroll
  for (int mm = 0; mm < 16; ++mm) {
    // snapshot current pair's GEMM1 results (register copy; SSA-renamed away)
    intx4 s1E[4], s1O[4];
    #pragma unroll
    for (int nt = 0; nt < 4; ++nt) { s1E[nt] = a1E[nt]; s1O[nt] = a1O[nt]; }

    // issue next pair's coef loads early (full STEP to cover L2 latency)
    uint4  wv4n = wv4c;
    float4 acEn = acEc, gcEn = gcEc, acOn = acOc, gcOn = gcOc;
    if (mm < 15) {
      wv4n = *(const uint4*)(wtl + (size_t)(mm + 1) * 4096);
      acEn = *(const float4*)(a2g + (2 * (mm + 1)) * 64 + kslc);
      gcEn = *(const float4*)(g2n + (2 * (mm + 1)) * 64 + kslc);
      acOn = *(const float4*)(a2g + (2 * (mm + 1) + 1) * 64 + kslc);
      gcOn = *(const float4*)(g2n + (2 * (mm + 1) + 1) * 64 + kslc);
    }

    // next pair's GEMM1 -- independent of EXPP/GEMM2 below (matrix pipe
    // overlaps VALU exp/pack of the current pair)
    if (mm < 15) {
      GEMM1PAIR()                   // pair mm+1 (tiles 2mm+2, 2mm+3)
    }
    if (mm < 14) {
      LOADCF(cfU, 2 * (mm + 2)) LOADCF(cfV, 2 * (mm + 2) + 1)  // pair mm+2
    }

    EXPP(s1E, acEc, gcEc, pE)
    EXPP(s1O, acOc, gcOc, pc)
    if (mm < 8) { GEMM2P(acc2m, wv4c) } else { GEMM2P(acc2s, wv4c) }

    wv4c = wv4n; acEc = acEn; gcEc = gcEn; acOc = acOn; gcOc = gcOn;
  }
#undef GEMM1PAIR
#undef EXPP
#undef GEMM2P
#undef LOADCF

  // ---- epilogue: cross-wave reduction (red aliases obs LDS; K-loop reads no LDS) ----
  // red[wv][b=64][a=68pad]; lane(c,q) reg r holds a = h*32+a2i*16+4q+r, b = nt*16+c
  {
    float* myr = red + wv * 4352;
    #pragma unroll
    for (int a2i = 0; a2i < 2; ++a2i)
      #pragma unroll
      for (int nt = 0; nt < 4; ++nt) {
        *(floatx4*)(myr + (nt * 16 + c) * 68 + a2i * 16 + 4 * q)      = acc2m[a2i][nt];
        *(floatx4*)(myr + (nt * 16 + c) * 68 + 32 + a2i * 16 + 4 * q) = acc2s[a2i][nt];
      }
  }
  __syncthreads();

  #pragma unroll
  for (int i = 0; i < 16; ++i) {
    int idx = tid + 256 * i;        // 0..4095
    int a = idx & 63;
    int b = idx >> 6;
    float v = red[b * 68 + a] + red[4352 + b * 68 + a] +
              red[8704 + b * 68 + a] + red[13056 + b * 68 + a];
    if (a < 32) {
      v += mbias[a];
    } else {
      v += sbias[a - 32];
      v = fminf(fmaxf(v, -20.f), 2.f);
      v = __builtin_amdgcn_exp2f(v * LOG2E);
    }
    out[(size_t)(row0 + b) * 64 + a] = v;
  }
}

extern "C" void kernel_launch(void* const* d_in, const int* in_sizes, int n_in,
                              void* d_out, int out_size, void* d_ws, size_t ws_size,
                              hipStream_t stream) {
  const float* obs = (const float*)d_in[0];
  const float* mC  = (const float*)d_in[1];
  const float* mS  = (const float*)d_in[2];
  const float* mW  = (const float*)d_in[3];
  const float* mB  = (const float*)d_in[4];
  const float* sC  = (const float*)d_in[5];
  const float* sS  = (const float*)d_in[6];
  const float* sW  = (const float*)d_in[7];
  const float* sB  = (const float*)d_in[8];
  float* out = (float*)d_out;

  // workspace: Cb2[2048*256] i8 (512KB) | a2g[2048] f32 | g2n[2048] f32 | wt[64KB]
  u8*    Cb2 = (u8*)d_ws;
  float* a2g = (float*)((char*)d_ws + 2048 * 256);
  float* g2n = a2g + 2048;
  u8*    wt  = (u8*)(g2n + 2048);

  prep<<<528, 256, 0, stream>>>(mC, mS, sC, sS, mW, sW, Cb2, a2g, g2n, wt);
  policy_main<<<512, 256, 0, stream>>>(obs, Cb2, a2g, g2n, wt, mB, sB, out);
}